// Round 4
// baseline (554.696 us; speedup 1.0000x reference)
//
#include <hip/hip_runtime.h>
#include <hip/hip_bf16.h>

// AugmentedTripletLoss on MI355X.
// inputs [8192,128] f32, targets [8192] int, center [16,128] f32 -> scalar loss.
//
// v4: back to v2's register-resident structure (v3's barrier-free LDS staging
// serialized on the DS queue: 177 us, both pipes idle). Changes vs v2:
//  - prep stores X pre-transposed into MFMA-fragment order xbfT[g][kc][lane]
//    so every A/B fragment load is a fully-coalesced 1KB/instruction stream.
//  - depth-2 register prefetch of B frags + per-column sq/targets.
//  - 2048 blocks (128 row-groups x 16 strips), launch_bounds(256,4).
//  - MFMA C-init = -sq_c/2 => acc = dot - sq_c/2 = w; dist2 = sq_r - 2w
//    (monotone -> sqrt deferred). Per-row stats merged via ordered-uint
//    atomicMin/Max; last block (ticket) computes the loss. Two launches total.

#define N_ROWS 8192
#define NPROTO 16
#define MARGIN_F 1.0f
#define EPS_F 1e-12f
#define NBLK_PD 2048
#define ENCP_INIT 0xFF800000u  // enc(+inf)
#define ENCN_INIT 0x007FFFFFu  // enc(-inf)

typedef __attribute__((ext_vector_type(8))) short short8;   // 8 bf16 = 4 VGPRs
typedef __attribute__((ext_vector_type(4))) float float4v;  // MFMA acc

static __device__ __forceinline__ unsigned f2bf(float f) {
  unsigned u = __float_as_uint(f);
  u += 0x7fffu + ((u >> 16) & 1u);  // RNE
  return u >> 16;
}
// order-preserving float<->uint for atomicMin/Max
static __device__ __forceinline__ unsigned encf(float f) {
  unsigned u = __float_as_uint(f);
  return (u & 0x80000000u) ? ~u : (u | 0x80000000u);
}
static __device__ __forceinline__ float decf(unsigned e) {
  unsigned u = (e & 0x80000000u) ? (e ^ 0x80000000u) : ~e;
  return __uint_as_float(u);
}

// xbfT layout: for 16-col group g (512 groups), k-chunk kc (4), lane (64):
//   16 bytes at g*4096 + kc*1024 + lane*16
//   = row (g*16 + (lane&15)), byte offset kc*64 + (lane>>4)*16 of row-major X.
// This is exactly the 16x16x32 MFMA A/B fragment for (l16=lane&15, q=lane>>4).

__global__ void prep_kernel(const float* __restrict__ x,
                            const float* __restrict__ center,
                            char* __restrict__ xbfT, float* __restrict__ sq,
                            float* __restrict__ mindc,
                            unsigned* __restrict__ pposU,
                            unsigned* __restrict__ pnegU,
                            unsigned* __restrict__ counter) {
  __shared__ float scn[NPROTO * 128];  // raw centers, 8 KB
  __shared__ float sinv[NPROTO];       // 1/||center_p||
  int tid = threadIdx.x;
#pragma unroll
  for (int j = 0; j < 8; ++j) scn[j * 256 + tid] = center[j * 256 + tid];
  __syncthreads();
  int rloc = tid >> 4, l = tid & 15;
  {  // center norms (redundant per block; 2k FLOP)
    const float* c = &scn[rloc * 128 + l * 8];
    float ss = 0.f;
#pragma unroll
    for (int j = 0; j < 8; ++j) ss += c[j] * c[j];
#pragma unroll
    for (int m = 1; m < 16; m <<= 1) ss += __shfl_xor(ss, m, 64);
    if (l == 0) sinv[rloc] = 1.0f / sqrtf(ss);
  }
  __syncthreads();
  int row = blockIdx.x * 16 + rloc;
  float4 v0 = ((const float4*)x)[row * 32 + l * 2];
  float4 v1 = ((const float4*)x)[row * 32 + l * 2 + 1];
  float ss = v0.x * v0.x + v0.y * v0.y + v0.z * v0.z + v0.w * v0.w +
             v1.x * v1.x + v1.y * v1.y + v1.z * v1.z + v1.w * v1.w;
  float dots[NPROTO];
#pragma unroll
  for (int p = 0; p < NPROTO; ++p) {
    const float* c = &scn[p * 128 + l * 8];
    dots[p] = v0.x * c[0] + v0.y * c[1] + v0.z * c[2] + v0.w * c[3] +
              v1.x * c[4] + v1.y * c[5] + v1.z * c[6] + v1.w * c[7];
  }
#pragma unroll
  for (int m = 1; m < 16; m <<= 1) {
    ss += __shfl_xor(ss, m, 64);
#pragma unroll
    for (int p = 0; p < NPROTO; ++p) dots[p] += __shfl_xor(dots[p], m, 64);
  }
  uint4 pk;
  pk.x = f2bf(v0.x) | (f2bf(v0.y) << 16);
  pk.y = f2bf(v0.z) | (f2bf(v0.w) << 16);
  pk.z = f2bf(v1.x) | (f2bf(v1.y) << 16);
  pk.w = f2bf(v1.z) | (f2bf(v1.w) << 16);
  // thread's 16B is k-chunk (kc=l>>2, q=l&3) of row (g*16+rloc)
  *(uint4*)(xbfT + blockIdx.x * 4096 + (l >> 2) * 1024 + ((l & 3) * 16 + rloc) * 16) = pk;
  if (l == 0) {
    float mind2 = INFINITY;
#pragma unroll
    for (int p = 0; p < NPROTO; ++p)
      mind2 = fminf(mind2, ss + 1.0f - 2.0f * dots[p] * sinv[p]);
    sq[row] = ss;
    mindc[row] = fmaxf(sqrtf(fmaxf(mind2, 0.0f)), EPS_F);
  }
  // init merge arrays + ticket (stream-ordered before pairdist)
  if (tid < 16) pposU[blockIdx.x * 16 + tid] = ENCP_INIT;
  else if (tid < 32) pnegU[blockIdx.x * 16 + tid - 16] = ENCN_INIT;
  if (blockIdx.x == 0 && tid == 32) *counter = 0u;
}

// 2048 blocks = 128 row-groups x 16 strips. Block = 4 waves; each wave holds
// A frags for all 64 block rows and owns 128 cols (8 tiles of 16) of the
// 512-col strip. All fragment loads are coalesced 1KB/instruction from xbfT.
__global__ __launch_bounds__(256, 4) void
pairdist_kernel(const char* __restrict__ xbfT, const float* __restrict__ sq,
                const int* __restrict__ tgt, const float* __restrict__ mindc,
                unsigned* __restrict__ pposU, unsigned* __restrict__ pnegU,
                unsigned* __restrict__ counter, float* __restrict__ out) {
  __shared__ float smrg[2][4][64];
  __shared__ float bsum[4];
  __shared__ int islast;
  int bid = blockIdx.x;
  int rg = bid >> 4, strip = bid & 15;
  int wave = threadIdx.x >> 6, lane = threadIdx.x & 63;
  int q = lane >> 4, l16 = lane & 15;
  int rowbase = rg * 64;
  int gb0 = strip * 32 + wave * 8;  // first 16-col group for this wave

  // A frags: coalesced from xbfT
  short8 a[4][4];
#pragma unroll
  for (int rt = 0; rt < 4; ++rt)
#pragma unroll
    for (int kc = 0; kc < 4; ++kc)
      a[rt][kc] = *(const short8*)(xbfT + (size_t)(rg * 4 + rt) * 4096 +
                                   kc * 1024 + lane * 16);
  // packed row targets (<64 -> 1 byte): byte r of trp[rt] = tgt[rowbase+rt*16+q*4+r]
  int trp[4];
#pragma unroll
  for (int rt = 0; rt < 4; ++rt) {
    int4 tv = ((const int4*)tgt)[(rowbase >> 2) + rt * 4 + q];
    trp[rt] = tv.x | (tv.y << 8) | (tv.z << 16) | (tv.w << 24);
  }

  float wpmin[16], wnmax[16];
#pragma unroll
  for (int i = 0; i < 16; ++i) { wpmin[i] = INFINITY; wnmax[i] = -INFINITY; }

  // depth-2 prefetch: 2-slot rotation, consume slot then reload it for t+2
  short8 breg[2][4];
  float sqv[2];
  int tgv[2];
#pragma unroll
  for (int p = 0; p < 2; ++p) {
    const char* bp = xbfT + (size_t)(gb0 + p) * 4096;
#pragma unroll
    for (int kc = 0; kc < 4; ++kc)
      breg[p][kc] = *(const short8*)(bp + kc * 1024 + lane * 16);
    sqv[p] = sq[(gb0 + p) * 16 + l16];
    tgv[p] = tgt[(gb0 + p) * 16 + l16] & 255;
  }

#pragma unroll
  for (int t = 0; t < 8; ++t) {
    int s = t & 1;
    float cini = -0.5f * sqv[s];
    int tcur = tgv[s];
    float4v acc[4];
#pragma unroll
    for (int rt = 0; rt < 4; ++rt) acc[rt] = (float4v){cini, cini, cini, cini};
#pragma unroll
    for (int kc = 0; kc < 4; ++kc)
#pragma unroll
      for (int rt = 0; rt < 4; ++rt)
        acc[rt] = __builtin_amdgcn_mfma_f32_16x16x32_bf16(a[rt][kc], breg[s][kc],
                                                          acc[rt], 0, 0, 0);
    if (t < 6) {  // reload this slot for tile t+2 (issues after MFMA consume)
      const char* bp = xbfT + (size_t)(gb0 + t + 2) * 4096;
#pragma unroll
      for (int kc = 0; kc < 4; ++kc)
        breg[s][kc] = *(const short8*)(bp + kc * 1024 + lane * 16);
      sqv[s] = sq[(gb0 + t + 2) * 16 + l16];
      tgv[s] = tgt[(gb0 + t + 2) * 16 + l16] & 255;
    }
    // epilogue: w = dot - sq_c/2; dist2 = sq_r - 2w ->
    // hardest positive = min w (same class), hardest negative = max w (diff)
#pragma unroll
    for (int rt = 0; rt < 4; ++rt) {
#pragma unroll
      for (int r = 0; r < 4; ++r) {
        int tb = (trp[rt] >> (8 * r)) & 255;
        float w = acc[rt][r];
        bool same = (tcur == tb);
        int idx = rt * 4 + r;
        wpmin[idx] = fminf(wpmin[idx], same ? w : INFINITY);
        wnmax[idx] = fmaxf(wnmax[idx], same ? -INFINITY : w);
      }
    }
  }

  // reduce across the 16 lanes of each quad
#pragma unroll
  for (int m = 1; m < 16; m <<= 1) {
#pragma unroll
    for (int i = 0; i < 16; ++i) {
      wpmin[i] = fminf(wpmin[i], __shfl_xor(wpmin[i], m, 64));
      wnmax[i] = fmaxf(wnmax[i], __shfl_xor(wnmax[i], m, 64));
    }
  }
  if (l16 == 0) {
#pragma unroll
    for (int rt = 0; rt < 4; ++rt)
#pragma unroll
      for (int r = 0; r < 4; ++r) {
        smrg[0][wave][rt * 16 + q * 4 + r] = wpmin[rt * 4 + r];
        smrg[1][wave][rt * 16 + q * 4 + r] = wnmax[rt * 4 + r];
      }
  }
  __syncthreads();
  if (threadIdx.x < 64) {
    int i = threadIdx.x;
    float wp = fminf(fminf(smrg[0][0][i], smrg[0][1][i]),
                     fminf(smrg[0][2][i], smrg[0][3][i]));
    float wn = fmaxf(fmaxf(smrg[1][0][i], smrg[1][1][i]),
                     fmaxf(smrg[1][2][i], smrg[1][3][i]));
    atomicMin(&pposU[rowbase + i], encf(wp));
    atomicMax(&pnegU[rowbase + i], encf(wn));
  }
  __threadfence();  // release our atomics
  __syncthreads();
  if (threadIdx.x == 0) islast = (atomicAdd(counter, 1u) == NBLK_PD - 1u);
  __syncthreads();
  if (!islast) return;
  __threadfence();  // acquire: all blocks' atomics visible
  float lsum = 0.f;
#pragma unroll 4
  for (int k = 0; k < N_ROWS / 256; ++k) {
    int i = k * 256 + threadIdx.x;
    unsigned ep = __hip_atomic_load(&pposU[i], __ATOMIC_RELAXED,
                                    __HIP_MEMORY_SCOPE_AGENT);
    unsigned en = __hip_atomic_load(&pnegU[i], __ATOMIC_RELAXED,
                                    __HIP_MEMORY_SCOPE_AGENT);
    float si = sq[i];
    float dap = sqrtf(fmaxf(fmaf(-2.0f, decf(ep), si), EPS_F));
    float dan = (en == ENCN_INIT)
                    ? (dap + MARGIN_F)
                    : sqrtf(fmaxf(fmaf(-2.0f, decf(en), si), EPS_F));
    dan = fminf(dan, mindc[i]);
    lsum += fmaxf(dap - dan + MARGIN_F, 0.0f);
  }
#pragma unroll
  for (int m = 1; m < 64; m <<= 1) lsum += __shfl_xor(lsum, m, 64);
  if (lane == 0) bsum[wave] = lsum;
  __syncthreads();
  if (threadIdx.x == 0)
    out[0] = (bsum[0] + bsum[1] + bsum[2] + bsum[3]) * (1.0f / (float)N_ROWS);
}

extern "C" void kernel_launch(void* const* d_in, const int* in_sizes, int n_in,
                              void* d_out, int out_size, void* d_ws, size_t ws_size,
                              hipStream_t stream) {
  const float* inputs = (const float*)d_in[0];
  const int* targets = (const int*)d_in[1];
  const float* center = (const float*)d_in[2];
  char* ws = (char*)d_ws;
  char* xbfT        = ws;                          // 2 MB fragment-order bf16 X
  float* sq         = (float*)(ws + 2097152);      // 32 KB
  float* mindc      = (float*)(ws + 2129920);      // 32 KB
  unsigned* pposU   = (unsigned*)(ws + 2162688);   // 32 KB  enc(min w | same)
  unsigned* pnegU   = (unsigned*)(ws + 2195456);   // 32 KB  enc(max w | diff)
  unsigned* counter = (unsigned*)(ws + 2228224);   // 4 B ticket
  float* out        = (float*)d_out;

  prep_kernel<<<512, 256, 0, stream>>>(inputs, center, xbfT, sq, mindc,
                                       pposU, pnegU, counter);
  pairdist_kernel<<<NBLK_PD, 256, 0, stream>>>(xbfT, sq, targets, mindc,
                                               pposU, pnegU, counter, out);
}

// Round 5
// 221.628 us; speedup vs baseline: 2.5028x; 2.5028x over previous
//
#include <hip/hip_runtime.h>
#include <hip/hip_bf16.h>

// AugmentedTripletLoss on MI355X.
// inputs [8192,128] f32, targets [8192] int, center [16,128] f32 -> scalar loss.
//
// v5: v4's fragment-ordered layout + depth-2 prefetch, but with per-wave
// register demand cut to ~110 VGPRs BY DESIGN (wave = 32 rows x 256 cols,
// 2x2 wave grid per 64x512 block) so 4 waves/SIMD fit naturally. No
// launch_bounds minimum (v4's (256,4) forced a 64-VGPR budget -> 590 MB of
// scratch spills -> 480 us). Two launches; fused ticket finalize.

#define N_ROWS 8192
#define NPROTO 16
#define MARGIN_F 1.0f
#define EPS_F 1e-12f
#define NBLK_PD 2048
#define ENCP_INIT 0xFF800000u  // enc(+inf)
#define ENCN_INIT 0x007FFFFFu  // enc(-inf)

typedef __attribute__((ext_vector_type(8))) short short8;   // 8 bf16 = 4 VGPRs
typedef __attribute__((ext_vector_type(4))) float float4v;  // MFMA acc

static __device__ __forceinline__ unsigned f2bf(float f) {
  unsigned u = __float_as_uint(f);
  u += 0x7fffu + ((u >> 16) & 1u);  // RNE
  return u >> 16;
}
// order-preserving float<->uint for atomicMin/Max
static __device__ __forceinline__ unsigned encf(float f) {
  unsigned u = __float_as_uint(f);
  return (u & 0x80000000u) ? ~u : (u | 0x80000000u);
}
static __device__ __forceinline__ float decf(unsigned e) {
  unsigned u = (e & 0x80000000u) ? (e ^ 0x80000000u) : ~e;
  return __uint_as_float(u);
}

// xbfT layout: for 16-col group g (512), k-chunk kc (4), lane (64):
//   16 bytes at g*4096 + kc*1024 + lane*16
//   = row (g*16 + (lane&15)), bytes [kc*64 + (lane>>4)*16, +16) of row-major X.
// Exactly the 16x16x32 MFMA A/B fragment for (l16=lane&15, q=lane>>4).

__global__ void prep_kernel(const float* __restrict__ x,
                            const float* __restrict__ center,
                            char* __restrict__ xbfT, float* __restrict__ sq,
                            float* __restrict__ mindc,
                            unsigned* __restrict__ pposU,
                            unsigned* __restrict__ pnegU,
                            unsigned* __restrict__ counter) {
  __shared__ float scn[NPROTO * 128];  // raw centers, 8 KB
  __shared__ float sinv[NPROTO];       // 1/||center_p||
  int tid = threadIdx.x;
#pragma unroll
  for (int j = 0; j < 8; ++j) scn[j * 256 + tid] = center[j * 256 + tid];
  __syncthreads();
  int rloc = tid >> 4, l = tid & 15;
  {  // center norms (redundant per block; 2k FLOP)
    const float* c = &scn[rloc * 128 + l * 8];
    float ss = 0.f;
#pragma unroll
    for (int j = 0; j < 8; ++j) ss += c[j] * c[j];
#pragma unroll
    for (int m = 1; m < 16; m <<= 1) ss += __shfl_xor(ss, m, 64);
    if (l == 0) sinv[rloc] = 1.0f / sqrtf(ss);
  }
  __syncthreads();
  int row = blockIdx.x * 16 + rloc;
  float4 v0 = ((const float4*)x)[row * 32 + l * 2];
  float4 v1 = ((const float4*)x)[row * 32 + l * 2 + 1];
  float ss = v0.x * v0.x + v0.y * v0.y + v0.z * v0.z + v0.w * v0.w +
             v1.x * v1.x + v1.y * v1.y + v1.z * v1.z + v1.w * v1.w;
  float dots[NPROTO];
#pragma unroll
  for (int p = 0; p < NPROTO; ++p) {
    const float* c = &scn[p * 128 + l * 8];
    dots[p] = v0.x * c[0] + v0.y * c[1] + v0.z * c[2] + v0.w * c[3] +
              v1.x * c[4] + v1.y * c[5] + v1.z * c[6] + v1.w * c[7];
  }
#pragma unroll
  for (int m = 1; m < 16; m <<= 1) {
    ss += __shfl_xor(ss, m, 64);
#pragma unroll
    for (int p = 0; p < NPROTO; ++p) dots[p] += __shfl_xor(dots[p], m, 64);
  }
  uint4 pk;
  pk.x = f2bf(v0.x) | (f2bf(v0.y) << 16);
  pk.y = f2bf(v0.z) | (f2bf(v0.w) << 16);
  pk.z = f2bf(v1.x) | (f2bf(v1.y) << 16);
  pk.w = f2bf(v1.z) | (f2bf(v1.w) << 16);
  // thread's 16B is k-chunk (kc=l>>2, q=l&3) of row (g*16+rloc)
  *(uint4*)(xbfT + blockIdx.x * 4096 + (l >> 2) * 1024 + ((l & 3) * 16 + rloc) * 16) = pk;
  if (l == 0) {
    float mind2 = INFINITY;
#pragma unroll
    for (int p = 0; p < NPROTO; ++p)
      mind2 = fminf(mind2, ss + 1.0f - 2.0f * dots[p] * sinv[p]);
    sq[row] = ss;
    mindc[row] = fmaxf(sqrtf(fmaxf(mind2, 0.0f)), EPS_F);
  }
  // init merge arrays + ticket (stream-ordered before pairdist)
  if (tid < 16) pposU[blockIdx.x * 16 + tid] = ENCP_INIT;
  else if (tid < 32) pnegU[blockIdx.x * 16 + tid - 16] = ENCN_INIT;
  if (blockIdx.x == 0 && tid == 32) *counter = 0u;
}

// 2048 blocks = 128 row-groups x 16 strips. Block = 64 rows x 512 cols.
// Wave (rh=wave&1, ch=wave>>1): rows rg*64 + rh*32 + [0,32), cols
// strip*512 + ch*256 + [0,256) as 16 tiles of 16. ~110 VGPRs/wave.
__global__ __launch_bounds__(256) void
pairdist_kernel(const char* __restrict__ xbfT, const float* __restrict__ sq,
                const int* __restrict__ tgt, const float* __restrict__ mindc,
                unsigned* __restrict__ pposU, unsigned* __restrict__ pnegU,
                unsigned* __restrict__ counter, float* __restrict__ out) {
  __shared__ float smrg[2][4][32];
  __shared__ float bsum[4];
  __shared__ int islast;
  int bid = blockIdx.x;
  int rg = bid >> 4, strip = bid & 15;
  int wave = threadIdx.x >> 6, lane = threadIdx.x & 63;
  int q = lane >> 4, l16 = lane & 15;
  int rowbase = rg * 64;
  int rh = wave & 1;   // row half
  int ch = wave >> 1;  // col half
  int gbase = strip * 32 + ch * 16;  // first 16-col group for this wave

  // A frags (coalesced 1KB/instruction): rows rowbase + rh*32 + rt*16 + l16
  short8 a[2][4];
#pragma unroll
  for (int rt = 0; rt < 2; ++rt)
#pragma unroll
    for (int kc = 0; kc < 4; ++kc)
      a[rt][kc] = *(const short8*)(xbfT + (size_t)(rg * 4 + rh * 2 + rt) * 4096 +
                                   kc * 1024 + lane * 16);
  // packed row targets (<64 -> 1 byte): byte r = tgt[rowbase + rh*32 + rt*16 + q*4 + r]
  int trp[2];
#pragma unroll
  for (int rt = 0; rt < 2; ++rt) {
    int4 tv = ((const int4*)tgt)[(rowbase >> 2) + rh * 8 + rt * 4 + q];
    trp[rt] = tv.x | (tv.y << 8) | (tv.z << 16) | (tv.w << 24);
  }

  float wpmin[8], wnmax[8];
#pragma unroll
  for (int i = 0; i < 8; ++i) { wpmin[i] = INFINITY; wnmax[i] = -INFINITY; }

  // depth-2 prefetch: 2-slot rotation, consume slot then reload it for t+2
  short8 breg[2][4];
  float sqv[2];
  int tgv[2];
#pragma unroll
  for (int p = 0; p < 2; ++p) {
    const char* bp = xbfT + (size_t)(gbase + p) * 4096;
#pragma unroll
    for (int kc = 0; kc < 4; ++kc)
      breg[p][kc] = *(const short8*)(bp + kc * 1024 + lane * 16);
    sqv[p] = sq[(gbase + p) * 16 + l16];
    tgv[p] = tgt[(gbase + p) * 16 + l16] & 255;
  }

#pragma unroll
  for (int t = 0; t < 16; ++t) {
    int s = t & 1;
    float cini = -0.5f * sqv[s];
    int tcur = tgv[s];
    float4v acc[2];
#pragma unroll
    for (int rt = 0; rt < 2; ++rt) acc[rt] = (float4v){cini, cini, cini, cini};
#pragma unroll
    for (int kc = 0; kc < 4; ++kc)
#pragma unroll
      for (int rt = 0; rt < 2; ++rt)
        acc[rt] = __builtin_amdgcn_mfma_f32_16x16x32_bf16(a[rt][kc], breg[s][kc],
                                                          acc[rt], 0, 0, 0);
    if (t < 14) {  // reload this slot for tile t+2 (issues after MFMA consume)
      const char* bp = xbfT + (size_t)(gbase + t + 2) * 4096;
#pragma unroll
      for (int kc = 0; kc < 4; ++kc)
        breg[s][kc] = *(const short8*)(bp + kc * 1024 + lane * 16);
      sqv[s] = sq[(gbase + t + 2) * 16 + l16];
      tgv[s] = tgt[(gbase + t + 2) * 16 + l16] & 255;
    }
    // epilogue: w = dot - sq_c/2; dist2 = sq_r - 2w ->
    // hardest positive = min w (same class), hardest negative = max w (diff)
#pragma unroll
    for (int rt = 0; rt < 2; ++rt) {
#pragma unroll
      for (int r = 0; r < 4; ++r) {
        int tb = (trp[rt] >> (8 * r)) & 255;
        float w = acc[rt][r];
        bool same = (tcur == tb);
        int idx = rt * 4 + r;
        wpmin[idx] = fminf(wpmin[idx], same ? w : INFINITY);
        wnmax[idx] = fmaxf(wnmax[idx], same ? -INFINITY : w);
      }
    }
  }

  // reduce across the 16 lanes of each quad
#pragma unroll
  for (int m = 1; m < 16; m <<= 1) {
#pragma unroll
    for (int i = 0; i < 8; ++i) {
      wpmin[i] = fminf(wpmin[i], __shfl_xor(wpmin[i], m, 64));
      wnmax[i] = fmaxf(wnmax[i], __shfl_xor(wnmax[i], m, 64));
    }
  }
  if (l16 == 0) {
#pragma unroll
    for (int rt = 0; rt < 2; ++rt)
#pragma unroll
      for (int r = 0; r < 4; ++r) {
        smrg[0][wave][rt * 16 + q * 4 + r] = wpmin[rt * 4 + r];
        smrg[1][wave][rt * 16 + q * 4 + r] = wnmax[rt * 4 + r];
      }
  }
  __syncthreads();
  if (threadIdx.x < 64) {
    int i = threadIdx.x;          // block-local row
    int rh2 = i >> 5, il = i & 31;
    // waves rh2 (ch=0) and rh2+2 (ch=1) cover this row
    float wp = fminf(smrg[0][rh2][il], smrg[0][rh2 + 2][il]);
    float wn = fmaxf(smrg[1][rh2][il], smrg[1][rh2 + 2][il]);
    atomicMin(&pposU[rowbase + i], encf(wp));
    atomicMax(&pnegU[rowbase + i], encf(wn));
  }
  __threadfence();  // release our atomics
  __syncthreads();
  if (threadIdx.x == 0) islast = (atomicAdd(counter, 1u) == NBLK_PD - 1u);
  __syncthreads();
  if (!islast) return;
  __threadfence();  // acquire: all blocks' atomics visible
  float lsum = 0.f;
#pragma unroll 4
  for (int k = 0; k < N_ROWS / 256; ++k) {
    int i = k * 256 + threadIdx.x;
    unsigned ep = __hip_atomic_load(&pposU[i], __ATOMIC_RELAXED,
                                    __HIP_MEMORY_SCOPE_AGENT);
    unsigned en = __hip_atomic_load(&pnegU[i], __ATOMIC_RELAXED,
                                    __HIP_MEMORY_SCOPE_AGENT);
    float si = sq[i];
    float dap = sqrtf(fmaxf(fmaf(-2.0f, decf(ep), si), EPS_F));
    float dan = (en == ENCN_INIT)
                    ? (dap + MARGIN_F)
                    : sqrtf(fmaxf(fmaf(-2.0f, decf(en), si), EPS_F));
    dan = fminf(dan, mindc[i]);
    lsum += fmaxf(dap - dan + MARGIN_F, 0.0f);
  }
#pragma unroll
  for (int m = 1; m < 64; m <<= 1) lsum += __shfl_xor(lsum, m, 64);
  if (lane == 0) bsum[wave] = lsum;
  __syncthreads();
  if (threadIdx.x == 0)
    out[0] = (bsum[0] + bsum[1] + bsum[2] + bsum[3]) * (1.0f / (float)N_ROWS);
}

extern "C" void kernel_launch(void* const* d_in, const int* in_sizes, int n_in,
                              void* d_out, int out_size, void* d_ws, size_t ws_size,
                              hipStream_t stream) {
  const float* inputs = (const float*)d_in[0];
  const int* targets = (const int*)d_in[1];
  const float* center = (const float*)d_in[2];
  char* ws = (char*)d_ws;
  char* xbfT        = ws;                          // 2 MB fragment-order bf16 X
  float* sq         = (float*)(ws + 2097152);      // 32 KB
  float* mindc      = (float*)(ws + 2129920);      // 32 KB
  unsigned* pposU   = (unsigned*)(ws + 2162688);   // 32 KB  enc(min w | same)
  unsigned* pnegU   = (unsigned*)(ws + 2195456);   // 32 KB  enc(max w | diff)
  unsigned* counter = (unsigned*)(ws + 2228224);   // 4 B ticket
  float* out        = (float*)d_out;

  prep_kernel<<<512, 256, 0, stream>>>(inputs, center, xbfT, sq, mindc,
                                       pposU, pnegU, counter);
  pairdist_kernel<<<NBLK_PD, 256, 0, stream>>>(xbfT, sq, targets, mindc,
                                               pposU, pnegU, counter, out);
}

// Round 6
// 161.687 us; speedup vs baseline: 3.4307x; 1.3707x over previous
//
#include <hip/hip_runtime.h>
#include <hip/hip_bf16.h>

// AugmentedTripletLoss on MI355X.
// inputs [8192,128] f32, targets [8192] int, center [16,128] f32 -> scalar loss.
//
// v6: v2's proven pairdist skeleton (50 us: rt=4 row-tiles/wave, 16 MFMA per
// B-tile, depth-1 prefetch, 1024 blocks = 128 rg x 8 strips) with ONE change:
// A/B fragment loads come from fragment-ordered xbfT (coalesced 1 KB/instr)
// instead of 16-row-scattered short8 loads. v5's regression is attributed to
// rt=2 + AGPR-funnel serialization of its deep prefetch, not the layout; this
// isolates the layout variable. Fused ticket finalize (2 launches, v5-proven).

#define N_ROWS 8192
#define NPROTO 16
#define MARGIN_F 1.0f
#define EPS_F 1e-12f
#define NBLK_PD 1024
#define ENCP_INIT 0xFF800000u  // enc(+inf)
#define ENCN_INIT 0x007FFFFFu  // enc(-inf)

typedef __attribute__((ext_vector_type(8))) short short8;   // 8 bf16 = 4 VGPRs
typedef __attribute__((ext_vector_type(4))) float float4v;  // MFMA acc

static __device__ __forceinline__ unsigned f2bf(float f) {
  unsigned u = __float_as_uint(f);
  u += 0x7fffu + ((u >> 16) & 1u);  // RNE
  return u >> 16;
}
// order-preserving float<->uint for atomicMin/Max
static __device__ __forceinline__ unsigned encf(float f) {
  unsigned u = __float_as_uint(f);
  return (u & 0x80000000u) ? ~u : (u | 0x80000000u);
}
static __device__ __forceinline__ float decf(unsigned e) {
  unsigned u = (e & 0x80000000u) ? (e ^ 0x80000000u) : ~e;
  return __uint_as_float(u);
}

// xbfT layout: for 16-col group g (512), k-chunk kc (4), lane (64):
//   16 bytes at g*4096 + kc*1024 + lane*16
//   = row (g*16 + (lane&15)), bytes [kc*64 + (lane>>4)*16, +16) of row-major X.
// Exactly the 16x16x32 MFMA A/B fragment for (l16=lane&15, q=lane>>4).

__global__ void prep_kernel(const float* __restrict__ x,
                            const float* __restrict__ center,
                            char* __restrict__ xbfT, float* __restrict__ sq,
                            float* __restrict__ mindc,
                            unsigned* __restrict__ pposU,
                            unsigned* __restrict__ pnegU,
                            unsigned* __restrict__ counter) {
  __shared__ float scn[NPROTO * 128];  // raw centers, 8 KB
  __shared__ float sinv[NPROTO];       // 1/||center_p||
  int tid = threadIdx.x;
#pragma unroll
  for (int j = 0; j < 8; ++j) scn[j * 256 + tid] = center[j * 256 + tid];
  __syncthreads();
  int rloc = tid >> 4, l = tid & 15;
  {  // center norms (redundant per block; 2k FLOP)
    const float* c = &scn[rloc * 128 + l * 8];
    float ss = 0.f;
#pragma unroll
    for (int j = 0; j < 8; ++j) ss += c[j] * c[j];
#pragma unroll
    for (int m = 1; m < 16; m <<= 1) ss += __shfl_xor(ss, m, 64);
    if (l == 0) sinv[rloc] = 1.0f / sqrtf(ss);
  }
  __syncthreads();
  int row = blockIdx.x * 16 + rloc;
  float4 v0 = ((const float4*)x)[row * 32 + l * 2];
  float4 v1 = ((const float4*)x)[row * 32 + l * 2 + 1];
  float ss = v0.x * v0.x + v0.y * v0.y + v0.z * v0.z + v0.w * v0.w +
             v1.x * v1.x + v1.y * v1.y + v1.z * v1.z + v1.w * v1.w;
  float dots[NPROTO];
#pragma unroll
  for (int p = 0; p < NPROTO; ++p) {
    const float* c = &scn[p * 128 + l * 8];
    dots[p] = v0.x * c[0] + v0.y * c[1] + v0.z * c[2] + v0.w * c[3] +
              v1.x * c[4] + v1.y * c[5] + v1.z * c[6] + v1.w * c[7];
  }
#pragma unroll
  for (int m = 1; m < 16; m <<= 1) {
    ss += __shfl_xor(ss, m, 64);
#pragma unroll
    for (int p = 0; p < NPROTO; ++p) dots[p] += __shfl_xor(dots[p], m, 64);
  }
  uint4 pk;
  pk.x = f2bf(v0.x) | (f2bf(v0.y) << 16);
  pk.y = f2bf(v0.z) | (f2bf(v0.w) << 16);
  pk.z = f2bf(v1.x) | (f2bf(v1.y) << 16);
  pk.w = f2bf(v1.z) | (f2bf(v1.w) << 16);
  // thread's 16B is k-chunk (kc=l>>2, q=l&3) of row (g*16+rloc)
  *(uint4*)(xbfT + blockIdx.x * 4096 + (l >> 2) * 1024 + ((l & 3) * 16 + rloc) * 16) = pk;
  if (l == 0) {
    float mind2 = INFINITY;
#pragma unroll
    for (int p = 0; p < NPROTO; ++p)
      mind2 = fminf(mind2, ss + 1.0f - 2.0f * dots[p] * sinv[p]);
    sq[row] = ss;
    mindc[row] = fmaxf(sqrtf(fmaxf(mind2, 0.0f)), EPS_F);
  }
  // init merge arrays + ticket (stream-ordered before pairdist)
  if (tid < 16) pposU[blockIdx.x * 16 + tid] = ENCP_INIT;
  else if (tid < 32) pnegU[blockIdx.x * 16 + tid - 16] = ENCN_INIT;
  if (blockIdx.x == 0 && tid == 32) *counter = 0u;
}

// 1024 blocks = 128 row-groups x 8 strips (v2's grid). Block = 4 waves; every
// wave holds A frags for all 64 block rows (loop-invariant -> AGPR-friendly)
// and owns 256 cols (16 tiles of 16) of the 1024-col strip. All fragment
// loads are coalesced 1 KB/instruction from xbfT.
__global__ __launch_bounds__(256) void
pairdist_kernel(const char* __restrict__ xbfT, const float* __restrict__ sq,
                const int* __restrict__ tgt, const float* __restrict__ mindc,
                unsigned* __restrict__ pposU, unsigned* __restrict__ pnegU,
                unsigned* __restrict__ counter, float* __restrict__ out) {
  __shared__ float smrg[2][4][64];
  __shared__ float bsum[4];
  __shared__ int islast;
  int bid = blockIdx.x;
  int rg = bid >> 3, strip = bid & 7;
  int wave = threadIdx.x >> 6, lane = threadIdx.x & 63;
  int q = lane >> 4, l16 = lane & 15;
  int rowbase = rg * 64;
  int gbase = strip * 64 + wave * 16;  // first 16-col group for this wave

  // A frags (coalesced, loop-invariant): groups rg*4+rt
  short8 a[4][4];
#pragma unroll
  for (int rt = 0; rt < 4; ++rt)
#pragma unroll
    for (int kc = 0; kc < 4; ++kc)
      a[rt][kc] = *(const short8*)(xbfT + (size_t)(rg * 4 + rt) * 4096 +
                                   kc * 1024 + lane * 16);
  // packed row targets (<64 -> 1 byte): byte r of trp[rt] = tgt[rowbase+rt*16+q*4+r]
  int trp[4];
#pragma unroll
  for (int rt = 0; rt < 4; ++rt) {
    int4 tv = ((const int4*)tgt)[(rowbase >> 2) + rt * 4 + q];
    trp[rt] = tv.x | (tv.y << 8) | (tv.z << 16) | (tv.w << 24);
  }

  float wpmin[16], wnmax[16];
#pragma unroll
  for (int i = 0; i < 16; ++i) { wpmin[i] = INFINITY; wnmax[i] = -INFINITY; }

  // depth-1 prefetch of B frags + per-column sq/target (v2 style)
  short8 bn[4];
  float sqn;
  int tcn;
  {
    const char* bp = xbfT + (size_t)gbase * 4096;
#pragma unroll
    for (int kc = 0; kc < 4; ++kc)
      bn[kc] = *(const short8*)(bp + kc * 1024 + lane * 16);
    sqn = sq[gbase * 16 + l16];
    tcn = tgt[gbase * 16 + l16] & 255;
  }

#pragma unroll
  for (int t = 0; t < 16; ++t) {
    short8 bc[4];
#pragma unroll
    for (int kc = 0; kc < 4; ++kc) bc[kc] = bn[kc];
    float sqc = sqn;
    int tc = tcn;
    int gnext = gbase + ((t + 1) & 15);  // wraps at t=15 (harmless reload)
    const char* bp = xbfT + (size_t)gnext * 4096;
#pragma unroll
    for (int kc = 0; kc < 4; ++kc)
      bn[kc] = *(const short8*)(bp + kc * 1024 + lane * 16);
    sqn = sq[gnext * 16 + l16];
    tcn = tgt[gnext * 16 + l16] & 255;

    // MFMA with C init = -sq_c/2  ->  acc = dot - sq_c/2 = w
    float cini = -0.5f * sqc;
    float4v acc[4];
#pragma unroll
    for (int rt = 0; rt < 4; ++rt) acc[rt] = (float4v){cini, cini, cini, cini};
#pragma unroll
    for (int kc = 0; kc < 4; ++kc)
#pragma unroll
      for (int rt = 0; rt < 4; ++rt)  // 4 independent acc chains
        acc[rt] = __builtin_amdgcn_mfma_f32_16x16x32_bf16(a[rt][kc], bc[kc],
                                                          acc[rt], 0, 0, 0);
    // epilogue: w = dot - sq_c/2; dist2 = sq_r - 2w ->
    // hardest positive = min w (same class), hardest negative = max w (diff)
#pragma unroll
    for (int rt = 0; rt < 4; ++rt) {
#pragma unroll
      for (int r = 0; r < 4; ++r) {
        int tb = (trp[rt] >> (8 * r)) & 255;
        float w = acc[rt][r];
        bool same = (tc == tb);
        int idx = rt * 4 + r;
        wpmin[idx] = fminf(wpmin[idx], same ? w : INFINITY);
        wnmax[idx] = fmaxf(wnmax[idx], same ? -INFINITY : w);
      }
    }
  }

  // reduce across the 16 lanes of each quad
#pragma unroll
  for (int m = 1; m < 16; m <<= 1) {
#pragma unroll
    for (int i = 0; i < 16; ++i) {
      wpmin[i] = fminf(wpmin[i], __shfl_xor(wpmin[i], m, 64));
      wnmax[i] = fmaxf(wnmax[i], __shfl_xor(wnmax[i], m, 64));
    }
  }
  if (l16 == 0) {
#pragma unroll
    for (int rt = 0; rt < 4; ++rt)
#pragma unroll
      for (int r = 0; r < 4; ++r) {
        smrg[0][wave][rt * 16 + q * 4 + r] = wpmin[rt * 4 + r];
        smrg[1][wave][rt * 16 + q * 4 + r] = wnmax[rt * 4 + r];
      }
  }
  __syncthreads();
  if (threadIdx.x < 64) {
    int i = threadIdx.x;
    float wp = fminf(fminf(smrg[0][0][i], smrg[0][1][i]),
                     fminf(smrg[0][2][i], smrg[0][3][i]));
    float wn = fmaxf(fmaxf(smrg[1][0][i], smrg[1][1][i]),
                     fmaxf(smrg[1][2][i], smrg[1][3][i]));
    atomicMin(&pposU[rowbase + i], encf(wp));
    atomicMax(&pnegU[rowbase + i], encf(wn));
  }
  __threadfence();  // release our atomics
  __syncthreads();
  if (threadIdx.x == 0) islast = (atomicAdd(counter, 1u) == NBLK_PD - 1u);
  __syncthreads();
  if (!islast) return;
  __threadfence();  // acquire: all blocks' atomics visible
  float lsum = 0.f;
#pragma unroll 4
  for (int k = 0; k < N_ROWS / 256; ++k) {
    int i = k * 256 + threadIdx.x;
    unsigned ep = __hip_atomic_load(&pposU[i], __ATOMIC_RELAXED,
                                    __HIP_MEMORY_SCOPE_AGENT);
    unsigned en = __hip_atomic_load(&pnegU[i], __ATOMIC_RELAXED,
                                    __HIP_MEMORY_SCOPE_AGENT);
    float si = sq[i];
    float dap = sqrtf(fmaxf(fmaf(-2.0f, decf(ep), si), EPS_F));
    float dan = (en == ENCN_INIT)
                    ? (dap + MARGIN_F)
                    : sqrtf(fmaxf(fmaf(-2.0f, decf(en), si), EPS_F));
    dan = fminf(dan, mindc[i]);
    lsum += fmaxf(dap - dan + MARGIN_F, 0.0f);
  }
#pragma unroll
  for (int m = 1; m < 64; m <<= 1) lsum += __shfl_xor(lsum, m, 64);
  if (lane == 0) bsum[wave] = lsum;
  __syncthreads();
  if (threadIdx.x == 0)
    out[0] = (bsum[0] + bsum[1] + bsum[2] + bsum[3]) * (1.0f / (float)N_ROWS);
}

extern "C" void kernel_launch(void* const* d_in, const int* in_sizes, int n_in,
                              void* d_out, int out_size, void* d_ws, size_t ws_size,
                              hipStream_t stream) {
  const float* inputs = (const float*)d_in[0];
  const int* targets = (const int*)d_in[1];
  const float* center = (const float*)d_in[2];
  char* ws = (char*)d_ws;
  char* xbfT        = ws;                          // 2 MB fragment-order bf16 X
  float* sq         = (float*)(ws + 2097152);      // 32 KB
  float* mindc      = (float*)(ws + 2129920);      // 32 KB
  unsigned* pposU   = (unsigned*)(ws + 2162688);   // 32 KB  enc(min w | same)
  unsigned* pnegU   = (unsigned*)(ws + 2195456);   // 32 KB  enc(max w | diff)
  unsigned* counter = (unsigned*)(ws + 2228224);   // 4 B ticket
  float* out        = (float*)d_out;

  prep_kernel<<<512, 256, 0, stream>>>(inputs, center, xbfT, sq, mindc,
                                       pposU, pnegU, counter);
  pairdist_kernel<<<NBLK_PD, 256, 0, stream>>>(xbfT, sq, targets, mindc,
                                               pposU, pnegU, counter, out);
}